// Round 12
// baseline (728.360 us; speedup 1.0000x reference)
//
#include <hip/hip_runtime.h>
#include <stdint.h>

// out[b,o,m] = sum_i in[b,i,m] * w[i,o,m]  (complex, fp32)
// B=32, Ci=Co=128, M=64*65=4160. One float2 per complex element.
//
// R12: lane = mode. Every mode is independent, so with 64 consecutive
// modes per wave the whole kernel is per-lane scalar: NO LDS, NO barriers,
// NO cross-lane ops, and every load/store is one contiguous 512B line.
// (R2-R11's LDS pipelines were pinned at ~2.7us per chunk = loaded-latency
// serialization, byte-count independent; R7's register streaming failed
// only because its lanes spanned b/o -> scattered 8B loads.)
// Wave tile: 4b x 8o x 64m (acc 64 VGPR). Block = 8 waves = all 32 b ->
// W-slice read exactly once (nontemporal); A re-read x16 served by XCD-L2
// (m-tile's 16 o-jobs ticket-adjacent on one XCD; same-k temporal reuse).
// Depth-2 rolling register prefetch over k (12 coalesced loads per k).

typedef float f2 __attribute__((ext_vector_type(2)));

#define CI 128
#define CO 128
#define MODES 4160

// acc.lo += a.lo*w.lo - a.hi*w.hi ; acc.hi += a.lo*w.hi + a.hi*w.lo
#define CFMA(acc, av, wv)                                                      \
  asm("v_pk_fma_f32 %0, %1, %2, %0 op_sel:[0,0,0] op_sel_hi:[0,1,1]"           \
      : "+v"(acc) : "v"(av), "v"(wv));                                         \
  asm("v_pk_fma_f32 %0, %1, %2, %0 op_sel:[1,1,0] op_sel_hi:[1,0,1] "          \
      "neg_lo:[1,0,0]"                                                         \
      : "+v"(acc) : "v"(av), "v"(wv));

#define LOADK(aa, ww, kk)                                                      \
  {                                                                            \
    _Pragma("unroll") for (int r = 0; r < 4; ++r)                              \
        aa[r] = Ab[((size_t)r * CI + (kk)) * MODES];                           \
    _Pragma("unroll") for (int q = 0; q < 8; ++q)                              \
        ww[q] = __builtin_nontemporal_load(&Wb[((size_t)(kk) * CO + q) * MODES]); \
  }

#define COMP(aa, ww)                                                           \
  _Pragma("unroll") for (int r = 0; r < 4; ++r)                                \
  _Pragma("unroll") for (int q = 0; q < 8; ++q) { CFMA(acc[r][q], aa[r], ww[q]); }

__global__ __launch_bounds__(512, 4)
void cmul2d_kernel(const f2* __restrict__ Ig,
                   const f2* __restrict__ Wl,
                   f2* __restrict__ Og) {
    const int t   = threadIdx.x;
    const int bid = blockIdx.x;

    // XCD-chunked job map: 1040 = 8 XCDs x 130. Within an XCD the 16
    // o-jobs of one m-tile are consecutive -> A m-slice (2MB) L2-shared.
    const int jid = (bid & 7) * 130 + (bid >> 3);
    const int mt  = jid >> 4;            // 0..64  m-tile (64 modes)
    const int ot  = jid & 15;            // o-tile (8 o)
    const int m0  = mt * 64;
    const int o0  = ot * 8;

    const int wave = t >> 6;             // 0..7 -> b-quad
    const int lane = t & 63;             // = mode within tile
    const int b0   = wave * 4;

    // per-lane bases: consecutive lanes -> consecutive modes (512B lines)
    const f2* Ab = Ig + ((size_t)b0 * CI) * MODES + m0 + lane;
    const f2* Wb = Wl + (size_t)o0 * MODES + m0 + lane;

    f2 acc[4][8];
#pragma unroll
    for (int r = 0; r < 4; ++r)
#pragma unroll
        for (int q = 0; q < 8; ++q) acc[r][q] = (f2)(0.0f);

    f2 a0[4], w0[8], a1[4], w1[8];
    LOADK(a0, w0, 0);                    // k = 0

#pragma unroll 1
    for (int k = 0; k < CI; k += 2) {
        LOADK(a1, w1, k + 1);            // issue k+1 (12 loads in flight)
        COMP(a0, w0);                    // compute k
        if (k + 2 < CI) LOADK(a0, w0, k + 2);
        COMP(a1, w1);                    // compute k+1
    }

    // stores: 64 lanes = 64 consecutive modes -> 512B lines, single-use
#pragma unroll
    for (int r = 0; r < 4; ++r) {
        const int b = b0 + r;
#pragma unroll
        for (int q = 0; q < 8; ++q) {
            __builtin_nontemporal_store(
                acc[r][q],
                &Og[((size_t)b * CO + o0 + q) * MODES + m0 + lane]);
        }
    }
}

extern "C" void kernel_launch(void* const* d_in, const int* in_sizes, int n_in,
                              void* d_out, int out_size, void* d_ws, size_t ws_size,
                              hipStream_t stream) {
    const f2* I = (const f2*)d_in[0];
    const f2* W = (const f2*)d_in[1];
    f2* O = (f2*)d_out;
    dim3 grid(1040);   // 65 m-tiles x 16 o-tiles
    dim3 block(512);   // 8 waves x (4b x 8o x 64m)
    cmul2d_kernel<<<grid, block, 0, stream>>>(I, W, O);
}